// Round 8
// baseline (119.866 us; speedup 1.0000x reference)
//
#include <hip/hip_runtime.h>

// Skeleton FK, algebraically simplified (frame-change G cancels):
//   q[c] = q[parent] + R[b,parent] @ v[c],  v[c] = (off[c][1], off[c][2], off[c][0])
//   out[b,c,:] = q[c]
//
// Round-8 = round-7 with the scratch spill eliminated. Every prior round
// staged output through fv[72] (+ro[72] in R7): ~144-288 staged floats
// spilled to scratch -> +151MB HBM write + +151MB read (the "2x WRITE_SIZE"
// seen since R1). Fix: build the 18 staged float4s directly from qx/qy/qz
// (compile-time component select), and fuse LDS readback into the global
// store (no DMA pending there -> no register staging needed).
//
// Structure: one 64-row tile per 1-wave block; all 44 gather-DMAs issued
// up front (bufA: matrices 0..9, stride 23; bufB: matrices 12..14 & 16..21
// compacted, stride 21); vmcnt(21) gates stage-A, vmcnt(0) gates stage-B;
// output staged in reused LDS (stride 19) then fully coalesced stores.

#define NJ 24

typedef const __attribute__((address_space(1))) void* gptr_t;
typedef __attribute__((address_space(3))) void* lptr_t;

#define WAITVM(n) asm volatile("s_waitcnt vmcnt(" #n ")" ::: "memory")

__global__ __launch_bounds__(64, 1) void fk_kernel(
    const float* __restrict__ ori,   // [B, 216]
    const float* __restrict__ off,   // [24, 3]
    float* __restrict__ out,         // [B, 72]
    int nt)
{
    const int l = threadIdx.x;                       // 0..63, one wave/block
    const long long tile = blockIdx.x;
    const float* __restrict__ gbase = ori + tile * (64LL * 216);

    __shared__ alignas(16) float4 s4[64 * 44];       // 45056 B
    float4* const bufA = s4;                         // stride 23 f4
    float4* const bufB = s4 + 64 * 23;               // stride 21 f4

    // ---- Issue ALL 44 DMAs up front (A's 23, then B's 21) ----
#pragma unroll
    for (int i = 0; i < 23; ++i) {
        const unsigned idx = (unsigned)(i * 64 + l);
        const unsigned row = idx / 23u;
        const unsigned w   = idx - row * 23u;
        const float* src = gbase + (size_t)row * 216u + (size_t)w * 4u;
        __builtin_amdgcn_global_load_lds((gptr_t)src, (lptr_t)(&bufA[i * 64]),
                                         16, 0, 0);
    }
#pragma unroll
    for (int i = 0; i < 21; ++i) {
        const unsigned idx = (unsigned)(i * 64 + l);
        const unsigned row = idx / 21u;
        const unsigned w   = idx - row * 21u;
        const unsigned g   = (w < 7u) ? (w + 27u) : (w + 29u);
        const float* src = gbase + (size_t)row * 216u + (size_t)g * 4u;
        __builtin_amdgcn_global_load_lds((gptr_t)src, (lptr_t)(&bufB[i * 64]),
                                         16, 0, 0);
    }

    float qx[NJ], qy[NJ], qz[NJ];
    qx[0] = 0.0f; qy[0] = 0.0f; qz[0] = 0.0f;

#define LOADM(rb, o) { \
    const float4 w0 = (rb)[(o)/4 + 0]; \
    const float4 w1 = (rb)[(o)/4 + 1]; \
    const float4 w2 = (rb)[(o)/4 + 2]; \
    const float tt[12] = {w0.x,w0.y,w0.z,w0.w, w1.x,w1.y,w1.z,w1.w, \
                          w2.x,w2.y,w2.z,w2.w}; \
    r[0]=tt[(o)%4+0]; r[1]=tt[(o)%4+1]; r[2]=tt[(o)%4+2]; \
    r[3]=tt[(o)%4+3]; r[4]=tt[(o)%4+4]; r[5]=tt[(o)%4+5]; \
    r[6]=tt[(o)%4+6]; r[7]=tt[(o)%4+7]; r[8]=tt[(o)%4+8]; }

#define CHILD(p, c) { \
    const float vx = off[3*(c)+1]; \
    const float vy = off[3*(c)+2]; \
    const float vz = off[3*(c)+0]; \
    qx[c] = fmaf(r[0], vx, fmaf(r[1], vy, fmaf(r[2], vz, qx[p]))); \
    qy[c] = fmaf(r[3], vx, fmaf(r[4], vy, fmaf(r[5], vz, qy[p]))); \
    qz[c] = fmaf(r[6], vx, fmaf(r[7], vy, fmaf(r[8], vz, qz[p]))); }

    // ---- Stage A: wait only for A's 23 DMAs (B's 21 still in flight) ----
    WAITVM(21);
    {
        const float4* __restrict__ rb = &bufA[l * 23];
        float r[9];
        LOADM(rb, 0);   CHILD(0, 1);  CHILD(0, 2);  CHILD(0, 3);
        LOADM(rb, 9);   CHILD(1, 4);
        LOADM(rb, 18);  CHILD(2, 5);
        LOADM(rb, 27);  CHILD(3, 6);
        LOADM(rb, 36);  CHILD(4, 7);
        LOADM(rb, 45);  CHILD(5, 8);
        LOADM(rb, 54);  CHILD(6, 9);
        LOADM(rb, 63);  CHILD(7, 10);
        LOADM(rb, 72);  CHILD(8, 11);
        LOADM(rb, 81);  CHILD(9, 12); CHILD(9, 13); CHILD(9, 14);
    }

    // ---- Stage B: B resident (latency hidden under stage A) ----
    WAITVM(0);
    {
        const float4* __restrict__ rb = &bufB[l * 21];
        float r[9];
        LOADM(rb, 0);   CHILD(12, 15);
        LOADM(rb, 9);   CHILD(13, 16);
        LOADM(rb, 18);  CHILD(14, 17);
        LOADM(rb, 28);  CHILD(16, 18);
        LOADM(rb, 37);  CHILD(17, 19);
        LOADM(rb, 46);  CHILD(18, 20);
        LOADM(rb, 55);  CHILD(19, 21);
        LOADM(rb, 64);  CHILD(20, 22);
        LOADM(rb, 73);  CHILD(21, 23);
    }
#undef LOADM
#undef CHILD

    // ---- Stage output directly from q registers (no fv[] staging array).
    // Output float e of the 72-float row = component e%3 of joint e/3;
    // all indices compile-time after unroll -> pure register selects.
#define QE(e) ( ((e) % 3) == 0 ? qx[(e) / 3] \
              : ((e) % 3) == 1 ? qy[(e) / 3] \
              :                  qz[(e) / 3] )

    float4* __restrict__ so4 = (float4*)s4;     // reuse, stride 19 f4
#pragma unroll
    for (int j = 0; j < 18; ++j)
        so4[l * 19 + j] = make_float4(QE(4*j + 0), QE(4*j + 1),
                                      QE(4*j + 2), QE(4*j + 3));
#undef QE

    // ---- Fused LDS-readback + fully coalesced global stores (18 x 1KB).
    // No register staging: no DMA is pending, nothing needs to be held.
    float4* __restrict__ o4 = (float4*)(out + tile * (64LL * 72));
#pragma unroll
    for (int j = 0; j < 18; ++j) {
        const unsigned g2   = (unsigned)(j * 64 + l);
        const unsigned row2 = g2 / 18u;
        const unsigned w2   = g2 - row2 * 18u;
        o4[g2] = so4[row2 * 19u + w2];
    }
}

extern "C" void kernel_launch(void* const* d_in, const int* in_sizes, int n_in,
                              void* d_out, int out_size, void* d_ws, size_t ws_size,
                              hipStream_t stream) {
    const float* ori = (const float*)d_in[0];   // [B,24,3,3] fp32
    const float* off = (const float*)d_in[1];   // [24,3] fp32
    float* out = (float*)d_out;                 // [B,24,3] fp32

    int B  = in_sizes[0] / 216;                 // 524288
    int nt = B / 64;                            // 8192 tiles
    hipLaunchKernelGGL(fk_kernel, dim3(nt), dim3(64), 0, stream,
                       ori, off, out, nt);
}

// Round 10
// 113.153 us; speedup vs baseline: 1.0593x; 1.0593x over previous
//
#include <hip/hip_runtime.h>

// Skeleton FK, algebraically simplified (frame-change G cancels):
//   q[c] = q[parent] + R[b,parent] @ v[c],  v[c] = (off[c][1], off[c][2], off[c][0])
//   out[b,c,:] = q[c]
//
// Round-10 = round-9 with the compile fix: __builtin_nontemporal_store
// requires a NATIVE vector pointer (clang ext_vector_type), not HIP's
// float4 class. Theory unchanged: output is write-once/read-never; nt
// stores skip L2/L3 allocation so ~151MB of input stays resident in the
// 256MB Infinity Cache across passes -> lower HBM FETCH per pass.
//
// Structure (unchanged from R8): one 64-row tile per 1-wave block; all 44
// gather-DMAs up front (bufA: matrices 0..9, stride 23 f4; bufB: matrices
// 12..14 & 16..21 compacted, stride 21 f4); vmcnt(21) gates stage-A,
// vmcnt(0) gates stage-B; output staged in reused LDS (stride 19 f4),
// then 18 fully-coalesced 1KB nt stores.

#define NJ 24

typedef const __attribute__((address_space(1))) void* gptr_t;
typedef __attribute__((address_space(3))) void* lptr_t;
typedef float __attribute__((ext_vector_type(4))) vf4;   // native vec for nt store

#define WAITVM(n) asm volatile("s_waitcnt vmcnt(" #n ")" ::: "memory")

__global__ __launch_bounds__(64, 1) void fk_kernel(
    const float* __restrict__ ori,   // [B, 216]
    const float* __restrict__ off,   // [24, 3]
    float* __restrict__ out,         // [B, 72]
    int nt)
{
    const int l = threadIdx.x;                       // 0..63, one wave/block
    const long long tile = blockIdx.x;
    const float* __restrict__ gbase = ori + tile * (64LL * 216);

    __shared__ alignas(16) float4 s4[64 * 44];       // 45056 B
    float4* const bufA = s4;                         // stride 23 f4
    float4* const bufB = s4 + 64 * 23;               // stride 21 f4

    // ---- Issue ALL 44 DMAs up front (A's 23, then B's 21) ----
#pragma unroll
    for (int i = 0; i < 23; ++i) {
        const unsigned idx = (unsigned)(i * 64 + l);
        const unsigned row = idx / 23u;
        const unsigned w   = idx - row * 23u;
        const float* src = gbase + (size_t)row * 216u + (size_t)w * 4u;
        __builtin_amdgcn_global_load_lds((gptr_t)src, (lptr_t)(&bufA[i * 64]),
                                         16, 0, 0);
    }
#pragma unroll
    for (int i = 0; i < 21; ++i) {
        const unsigned idx = (unsigned)(i * 64 + l);
        const unsigned row = idx / 21u;
        const unsigned w   = idx - row * 21u;
        const unsigned g   = (w < 7u) ? (w + 27u) : (w + 29u);
        const float* src = gbase + (size_t)row * 216u + (size_t)g * 4u;
        __builtin_amdgcn_global_load_lds((gptr_t)src, (lptr_t)(&bufB[i * 64]),
                                         16, 0, 0);
    }

    float qx[NJ], qy[NJ], qz[NJ];
    qx[0] = 0.0f; qy[0] = 0.0f; qz[0] = 0.0f;

#define LOADM(rb, o) { \
    const float4 w0 = (rb)[(o)/4 + 0]; \
    const float4 w1 = (rb)[(o)/4 + 1]; \
    const float4 w2 = (rb)[(o)/4 + 2]; \
    const float tt[12] = {w0.x,w0.y,w0.z,w0.w, w1.x,w1.y,w1.z,w1.w, \
                          w2.x,w2.y,w2.z,w2.w}; \
    r[0]=tt[(o)%4+0]; r[1]=tt[(o)%4+1]; r[2]=tt[(o)%4+2]; \
    r[3]=tt[(o)%4+3]; r[4]=tt[(o)%4+4]; r[5]=tt[(o)%4+5]; \
    r[6]=tt[(o)%4+6]; r[7]=tt[(o)%4+7]; r[8]=tt[(o)%4+8]; }

#define CHILD(p, c) { \
    const float vx = off[3*(c)+1]; \
    const float vy = off[3*(c)+2]; \
    const float vz = off[3*(c)+0]; \
    qx[c] = fmaf(r[0], vx, fmaf(r[1], vy, fmaf(r[2], vz, qx[p]))); \
    qy[c] = fmaf(r[3], vx, fmaf(r[4], vy, fmaf(r[5], vz, qy[p]))); \
    qz[c] = fmaf(r[6], vx, fmaf(r[7], vy, fmaf(r[8], vz, qz[p]))); }

    // ---- Stage A: wait only for A's 23 DMAs (B's 21 still in flight) ----
    WAITVM(21);
    {
        const float4* __restrict__ rb = &bufA[l * 23];
        float r[9];
        LOADM(rb, 0);   CHILD(0, 1);  CHILD(0, 2);  CHILD(0, 3);
        LOADM(rb, 9);   CHILD(1, 4);
        LOADM(rb, 18);  CHILD(2, 5);
        LOADM(rb, 27);  CHILD(3, 6);
        LOADM(rb, 36);  CHILD(4, 7);
        LOADM(rb, 45);  CHILD(5, 8);
        LOADM(rb, 54);  CHILD(6, 9);
        LOADM(rb, 63);  CHILD(7, 10);
        LOADM(rb, 72);  CHILD(8, 11);
        LOADM(rb, 81);  CHILD(9, 12); CHILD(9, 13); CHILD(9, 14);
    }

    // ---- Stage B: B resident (latency hidden under stage A) ----
    WAITVM(0);
    {
        const float4* __restrict__ rb = &bufB[l * 21];
        float r[9];
        LOADM(rb, 0);   CHILD(12, 15);
        LOADM(rb, 9);   CHILD(13, 16);
        LOADM(rb, 18);  CHILD(14, 17);
        LOADM(rb, 28);  CHILD(16, 18);
        LOADM(rb, 37);  CHILD(17, 19);
        LOADM(rb, 46);  CHILD(18, 20);
        LOADM(rb, 55);  CHILD(19, 21);
        LOADM(rb, 64);  CHILD(20, 22);
        LOADM(rb, 73);  CHILD(21, 23);
    }
#undef LOADM
#undef CHILD

    // ---- Stage output directly from q registers (compile-time selects) ----
#define QE(e) ( ((e) % 3) == 0 ? qx[(e) / 3] \
              : ((e) % 3) == 1 ? qy[(e) / 3] \
              :                  qz[(e) / 3] )

    float4* __restrict__ so4 = (float4*)s4;     // reuse, stride 19 f4
#pragma unroll
    for (int j = 0; j < 18; ++j)
        so4[l * 19 + j] = make_float4(QE(4*j + 0), QE(4*j + 1),
                                      QE(4*j + 2), QE(4*j + 3));
#undef QE

    // ---- Fused LDS-readback + coalesced NON-TEMPORAL stores (18 x 1KB).
    // nt: bypass L2/L3 allocation -- output is never read, keep the L3
    // full of input instead.
    vf4* __restrict__ o4 = (vf4*)(out + tile * (64LL * 72));
#pragma unroll
    for (int j = 0; j < 18; ++j) {
        const unsigned g2   = (unsigned)(j * 64 + l);
        const unsigned row2 = g2 / 18u;
        const unsigned w2   = g2 - row2 * 18u;
        const float4 v = so4[row2 * 19u + w2];
        vf4 nv; nv.x = v.x; nv.y = v.y; nv.z = v.z; nv.w = v.w;
        __builtin_nontemporal_store(nv, &o4[g2]);
    }
}

extern "C" void kernel_launch(void* const* d_in, const int* in_sizes, int n_in,
                              void* d_out, int out_size, void* d_ws, size_t ws_size,
                              hipStream_t stream) {
    const float* ori = (const float*)d_in[0];   // [B,24,3,3] fp32
    const float* off = (const float*)d_in[1];   // [24,3] fp32
    float* out = (float*)d_out;                 // [B,24,3] fp32

    int B  = in_sizes[0] / 216;                 // 524288
    int nt = B / 64;                            // 8192 tiles
    hipLaunchKernelGGL(fk_kernel, dim3(nt), dim3(64), 0, stream,
                       ori, off, out, nt);
}